// Round 4
// baseline (335.639 us; speedup 1.0000x reference)
//
#include <hip/hip_runtime.h>

#define NN 100000
#define KK 16
#define DD 128
#define DEE 32
#define DTT 32
#define C1 192        // D + DE + DT
#define BN 32         // nodes per block
#define AB 200        // aggb row stride in shorts (192 + 8 pad)
#define A2B 264       // a2b row stride in shorts (256 + 8 pad)
#define GRID (NN / BN)          // 3125 tgn blocks
#define SUMB 625                // sum-role blocks in mega kernel (NN/160)

// transformed-weight region: per layer, W1T = 24*128*8 = 24576, W2T = 32*128*8 = 32768
#define W1T_SH 24576
#define WLAYER_SH 57344                  // shorts per layer
#define WTOT_SH (2 * WLAYER_SH)          // 114688 shorts = 229376 B
#define TMP_OFF_B 229376                 // bf16 layer-0 out
#define TMP_B (NN * DD * 2)              // 25.6 MB
#define SUMS_OFF_B (TMP_OFF_B + TMP_B)   // bf16 layer-1 [N][64] edge|time sums
#define SUMS_B (NN * 64 * 2)             // 12.8 MB

typedef __attribute__((ext_vector_type(8))) short bfrag;    // 8 bf16 = 4 VGPR
typedef __attribute__((ext_vector_type(4))) float f32x4;    // MFMA C/D
typedef __attribute__((ext_vector_type(4))) short short4v;  // 8-byte chunk

__device__ __forceinline__ short f2bf(float x) {  // RNE f32 -> bf16 bits
  unsigned u = __builtin_bit_cast(unsigned, x);
  unsigned r = u + 0x7fffu + ((u >> 16) & 1u);
  return (short)(r >> 16);
}
__device__ __forceinline__ float bf2f(short s) {
  unsigned u = ((unsigned)(unsigned short)s) << 16;
  return __builtin_bit_cast(float, u);
}

// ---- prep: W1/W2 (both layers) -> bf16 fragment-major [kg][col][8] ----
__global__ void prep_weights(const float* __restrict__ W1, const float* __restrict__ W2,
                             short* __restrict__ out) {
  const int t = blockIdx.x * 256 + threadIdx.x;
  const int l = t / WLAYER_SH;
  const int r = t % WLAYER_SH;
  float v;
  if (r < W1T_SH) {
    const int kg = r >> 10, col = (r >> 3) & 127, j = r & 7;
    v = W1[(size_t)l * C1 * DD + (size_t)(kg * 8 + j) * DD + col];
  } else {
    const int r2 = r - W1T_SH;
    const int kg = r2 >> 10, col = (r2 >> 3) & 127, j = r2 & 7;
    v = W2[(size_t)l * 2 * DD * DD + (size_t)(kg * 8 + j) * DD + col];
  }
  out[t] = f2bf(v);
}

// ---- sum-role: one wave per node; full-BW stream of edge+time rows, xor-reduce ----
__device__ __forceinline__ void sum_role(int sid, const float* __restrict__ edge,
                                         const float* __restrict__ timef,
                                         short* __restrict__ sums) {
  const int t = threadIdx.x;
  const int lane = t & 63, wv = t >> 6;
  const int nbase = sid * 160 + wv * 40;
  for (int k = 0; k < 40; ++k) {
    const int n = nbase + k;
    const float4* ep = reinterpret_cast<const float4*>(edge  + (size_t)n * (KK * DEE));
    const float4* tp = reinterpret_cast<const float4*>(timef + (size_t)n * (KK * DTT));
    const float4 e0 = ep[lane], e1 = ep[lane + 64];
    const float4 t0 = tp[lane], t1 = tp[lane + 64];
    float es[4] = {e0.x + e1.x, e0.y + e1.y, e0.z + e1.z, e0.w + e1.w};
    float ts[4] = {t0.x + t1.x, t0.y + t1.y, t0.z + t1.z, t0.w + t1.w};
    #pragma unroll
    for (int m = 8; m <= 32; m <<= 1) {
      #pragma unroll
      for (int i = 0; i < 4; ++i) {
        es[i] += __shfl_xor(es[i], m, 64);
        ts[i] += __shfl_xor(ts[i], m, 64);
      }
    }
    if (lane < 16) {
      const float* src = (lane < 8) ? es : ts;
      short4v o;
      #pragma unroll
      for (int i = 0; i < 4; ++i) o[i] = f2bf(src[i]);
      *reinterpret_cast<short4v*>(sums + (size_t)n * 64 + (lane >> 3) * 32 + (lane & 7) * 4) = o;
    }
  }
}

// ---- tgn block body. INBF: prev bf16. OUTBF: out bf16. PRESUM: sums precomputed ----
template<bool INBF, bool OUTBF, bool PRESUM>
__device__ __forceinline__ void tgn_block(
    int bid, const void* __restrict__ prev_,
    const float* __restrict__ edge, const float* __restrict__ timef,
    const short* __restrict__ sums,
    const short* __restrict__ wT, const float* __restrict__ b1g,
    const float* __restrict__ b2g, const int* __restrict__ idxg,
    void* __restrict__ out_,
    short (*aggb)[AB], short (*a2b)[A2B])
{
  const int t  = threadIdx.x;
  const int n0 = bid * BN;

  // stage this block's own prev rows -> a2b[:, 0:128]
  {
    const int d4 = (t & 31) * 4;
    for (int nl = t >> 5; nl < BN; nl += 8) {
      short4v o;
      if constexpr (INBF) {
        o = *reinterpret_cast<const short4v*>((const short*)prev_ + (size_t)(n0 + nl) * DD + d4);
      } else {
        const float4 v = *reinterpret_cast<const float4*>((const float*)prev_ + (size_t)(n0 + nl) * DD + d4);
        o[0] = f2bf(v.x); o[1] = f2bf(v.y); o[2] = f2bf(v.z); o[3] = f2bf(v.w);
      }
      *reinterpret_cast<short4v*>(&a2b[nl][d4]) = o;
    }
  }

  // edge/time sums -> aggb[:, 128:192]
  if constexpr (PRESUM) {
    const bfrag s = *reinterpret_cast<const bfrag*>(sums + (size_t)n0 * 64 + t * 8);
    *reinterpret_cast<bfrag*>(&aggb[t >> 3][DD + (t & 7) * 8]) = s;
  } else {
    const int c4 = (t & 7) * 4;
    const int nl = t >> 3;
    const float* ep = edge  + (size_t)(n0 + nl) * KK * DEE + c4;
    const float* tp = timef + (size_t)(n0 + nl) * KK * DTT + c4;
    float e0=0,e1=0,e2=0,e3=0, s0=0,s1=0,s2=0,s3=0;
    #pragma unroll
    for (int j = 0; j < KK; ++j) {
      const float4 ev = *reinterpret_cast<const float4*>(ep + j * DEE);
      const float4 tv = *reinterpret_cast<const float4*>(tp + j * DTT);
      e0 += ev.x; e1 += ev.y; e2 += ev.z; e3 += ev.w;
      s0 += tv.x; s1 += tv.y; s2 += tv.z; s3 += tv.w;
    }
    short4v eo; eo[0]=f2bf(e0); eo[1]=f2bf(e1); eo[2]=f2bf(e2); eo[3]=f2bf(e3);
    short4v so; so[0]=f2bf(s0); so[1]=f2bf(s1); so[2]=f2bf(s2); so[3]=f2bf(s3);
    *reinterpret_cast<short4v*>(&aggb[nl][DD + c4])       = eo;
    *reinterpret_cast<short4v*>(&aggb[nl][DD + DEE + c4]) = so;
  }

  // neighbor gather-sum -> aggb[:, 0:128]
  {
    const int d4 = (t & 31) * 4;
    for (int nl = t >> 5; nl < BN; nl += 8) {
      const int4* ip = reinterpret_cast<const int4*>(idxg + (size_t)(n0 + nl) * KK);
      const int4 i0 = ip[0], i1 = ip[1], i2 = ip[2], i3 = ip[3];
      const int rows[16] = {i0.x, i0.y, i0.z, i0.w, i1.x, i1.y, i1.z, i1.w,
                            i2.x, i2.y, i2.z, i2.w, i3.x, i3.y, i3.z, i3.w};
      float a0=0, a1=0, a2=0, a3=0;
      #pragma unroll
      for (int j = 0; j < 16; ++j) {
        if constexpr (INBF) {
          const short4v v = *reinterpret_cast<const short4v*>((const short*)prev_ + (size_t)rows[j] * DD + d4);
          a0 += bf2f(v[0]); a1 += bf2f(v[1]); a2 += bf2f(v[2]); a3 += bf2f(v[3]);
        } else {
          const float4 v = *reinterpret_cast<const float4*>((const float*)prev_ + (size_t)rows[j] * DD + d4);
          a0 += v.x; a1 += v.y; a2 += v.z; a3 += v.w;
        }
      }
      short4v o; o[0]=f2bf(a0); o[1]=f2bf(a1); o[2]=f2bf(a2); o[3]=f2bf(a3);
      *reinterpret_cast<short4v*>(&aggb[nl][d4]) = o;
    }
  }
  __syncthreads();

  const int lane = t & 63;
  const int wv   = t >> 6;
  const int lr   = lane & 15;
  const int lg   = lane >> 4;
  const int n0w  = wv * 32;

  // ---- GEMM1: h = relu(aggb @ W1 + b1) -> a2b[:, 128:256] ----
  {
    f32x4 acc[2][2];
    #pragma unroll
    for (int nt = 0; nt < 2; ++nt) {
      const float bv = b1g[n0w + nt * 16 + lr];
      acc[0][nt] = (f32x4){bv, bv, bv, bv};
      acc[1][nt] = (f32x4){bv, bv, bv, bv};
    }
    #pragma unroll
    for (int ks = 0; ks < 6; ++ks) {
      const bfrag a0 = *reinterpret_cast<const bfrag*>(&aggb[lr][ks * 32 + lg * 8]);
      const bfrag a1 = *reinterpret_cast<const bfrag*>(&aggb[16 + lr][ks * 32 + lg * 8]);
      const short* wp = wT + ((size_t)((ks * 4 + lg) * 128) + n0w + lr) * 8;
      const bfrag bb0 = *reinterpret_cast<const bfrag*>(wp);
      const bfrag bb1 = *reinterpret_cast<const bfrag*>(wp + 16 * 8);
      acc[0][0] = __builtin_amdgcn_mfma_f32_16x16x32_bf16(a0, bb0, acc[0][0], 0, 0, 0);
      acc[1][0] = __builtin_amdgcn_mfma_f32_16x16x32_bf16(a1, bb0, acc[1][0], 0, 0, 0);
      acc[0][1] = __builtin_amdgcn_mfma_f32_16x16x32_bf16(a0, bb1, acc[0][1], 0, 0, 0);
      acc[1][1] = __builtin_amdgcn_mfma_f32_16x16x32_bf16(a1, bb1, acc[1][1], 0, 0, 0);
    }
    #pragma unroll
    for (int mt = 0; mt < 2; ++mt)
      #pragma unroll
      for (int nt = 0; nt < 2; ++nt)
        #pragma unroll
        for (int r = 0; r < 4; ++r)
          a2b[mt * 16 + lg * 4 + r][DD + n0w + nt * 16 + lr] = f2bf(fmaxf(acc[mt][nt][r], 0.f));
  }
  __syncthreads();

  // ---- GEMM2: out = a2b @ W2 + b2 ----
  {
    const short* w2T = wT + W1T_SH;
    f32x4 acc[2][2];
    #pragma unroll
    for (int nt = 0; nt < 2; ++nt) {
      const float bv = b2g[n0w + nt * 16 + lr];
      acc[0][nt] = (f32x4){bv, bv, bv, bv};
      acc[1][nt] = (f32x4){bv, bv, bv, bv};
    }
    #pragma unroll
    for (int ks = 0; ks < 8; ++ks) {
      const bfrag a0 = *reinterpret_cast<const bfrag*>(&a2b[lr][ks * 32 + lg * 8]);
      const bfrag a1 = *reinterpret_cast<const bfrag*>(&a2b[16 + lr][ks * 32 + lg * 8]);
      const short* wp = w2T + ((size_t)((ks * 4 + lg) * 128) + n0w + lr) * 8;
      const bfrag bb0 = *reinterpret_cast<const bfrag*>(wp);
      const bfrag bb1 = *reinterpret_cast<const bfrag*>(wp + 16 * 8);
      acc[0][0] = __builtin_amdgcn_mfma_f32_16x16x32_bf16(a0, bb0, acc[0][0], 0, 0, 0);
      acc[1][0] = __builtin_amdgcn_mfma_f32_16x16x32_bf16(a1, bb0, acc[1][0], 0, 0, 0);
      acc[0][1] = __builtin_amdgcn_mfma_f32_16x16x32_bf16(a0, bb1, acc[0][1], 0, 0, 0);
      acc[1][1] = __builtin_amdgcn_mfma_f32_16x16x32_bf16(a1, bb1, acc[1][1], 0, 0, 0);
    }
    #pragma unroll
    for (int mt = 0; mt < 2; ++mt)
      #pragma unroll
      for (int nt = 0; nt < 2; ++nt)
        #pragma unroll
        for (int r = 0; r < 4; ++r) {
          const float v = acc[mt][nt][r];
          const size_t grow = (size_t)(n0 + mt * 16 + lg * 4 + r);
          const int    gcol = n0w + nt * 16 + lr;
          if constexpr (OUTBF) ((short*)out_)[grow * DD + gcol] = f2bf(v);
          else                 ((float*)out_)[grow * DD + gcol] = v;
        }
  }
}

// ---- mega kernel: layer-0 tgn blocks interleaved with layer-1 sum blocks ----
__global__ __launch_bounds__(256, 5) void mega0(
    const float* __restrict__ features,
    const float* __restrict__ edge0, const float* __restrict__ time0,
    const float* __restrict__ edge1, const float* __restrict__ time1,
    const short* __restrict__ wT, const float* __restrict__ b1,
    const float* __restrict__ b2, const int* __restrict__ idx0,
    short* __restrict__ tmp, short* __restrict__ sums1)
{
  __shared__ short aggb[BN][AB];
  __shared__ short a2b[BN][A2B];
  const int b = blockIdx.x;
  const int r = b % 6;
  if (r == 5) {                       // every 6th block: stream layer-1 sums
    sum_role(b / 6, edge1, time1, sums1);
    return;
  }
  const int tb = (b / 6) * 5 + r;     // tgn tile id 0..3124
  tgn_block<false, true, false>(tb, features, edge0, time0, nullptr,
                                wT, b1, b2, idx0, tmp, aggb, a2b);
}

// ---- layer-1 kernel: no streaming, uses precomputed sums ----
__global__ __launch_bounds__(256, 5) void tgn1(
    const short* __restrict__ tmp, const short* __restrict__ sums1,
    const short* __restrict__ wT, const float* __restrict__ b1,
    const float* __restrict__ b2, const int* __restrict__ idx1,
    float* __restrict__ outp)
{
  __shared__ short aggb[BN][AB];
  __shared__ short a2b[BN][A2B];
  tgn_block<true, false, true>(blockIdx.x, tmp, nullptr, nullptr, sums1,
                               wT, b1, b2, idx1, outp, aggb, a2b);
}

extern "C" void kernel_launch(void* const* d_in, const int* in_sizes, int n_in,
                              void* d_out, int out_size, void* d_ws, size_t ws_size,
                              hipStream_t stream) {
  const float* features = (const float*)d_in[0];
  const float* edge     = (const float*)d_in[1];
  const float* timef    = (const float*)d_in[2];
  const float* W1       = (const float*)d_in[3];
  const float* b1       = (const float*)d_in[4];
  const float* W2       = (const float*)d_in[5];
  const float* b2       = (const float*)d_in[6];
  const int*   idx      = (const int*)d_in[7];
  float* outp = (float*)d_out;

  short* wT    = (short*)d_ws;
  short* tmp   = (short*)((char*)d_ws + TMP_OFF_B);
  short* sums1 = (short*)((char*)d_ws + SUMS_OFF_B);

  dim3 block(256);

  prep_weights<<<dim3(WTOT_SH / 256), block, 0, stream>>>(W1, W2, wT);

  mega0<<<dim3(GRID + SUMB), block, 0, stream>>>(
      features, edge, timef,
      edge  + (size_t)NN * KK * DEE,
      timef + (size_t)NN * KK * DTT,
      wT, b1, b2, idx, tmp, sums1);

  tgn1<<<dim3(GRID), block, 0, stream>>>(
      tmp, sums1, wT + WLAYER_SH, b1 + DD, b2 + DD,
      idx + (size_t)NN * KK, outp);
}

// Round 5
// 295.594 us; speedup vs baseline: 1.1355x; 1.1355x over previous
//
#include <hip/hip_runtime.h>

#define NN 100000
#define KK 16
#define DD 128
#define DEE 32
#define DTT 32
#define C1 192        // D + DE + DT
#define BN 32         // nodes per block
#define AB 200        // aggb row stride in shorts (192 + 8 pad); 400 B ≡ 4 words mod 32 banks
#define HB 136        // h row stride in shorts (128 + 8 pad);   272 B ≡ 4 words mod 32 banks
#define GRID (NN / BN)

// transformed-weight region: per layer, W1T = 24*128*8 = 24576, W2T = 32*128*8 = 32768
#define W1T_SH 24576
#define WLAYER_SH 57344                  // shorts per layer
#define WTOT_SH (2 * WLAYER_SH)          // 229376 B total
#define TMP_OFF_B 229376                 // bf16 layer-0 out
#define TMP_B (NN * DD * 2)              // 25.6 MB
#define FBF_OFF_B (TMP_OFF_B + TMP_B)    // bf16 features
#define FBF_B (NN * DD * 2)

typedef __attribute__((ext_vector_type(8))) short bfrag;    // 8 bf16 = 4 VGPR (MFMA A/B)
typedef __attribute__((ext_vector_type(4))) float f32x4;    // MFMA C/D
typedef __attribute__((ext_vector_type(4))) short short4v;  // 8-byte chunk

__device__ __forceinline__ short f2bf(float x) {  // RNE f32 -> bf16 bits
  unsigned u = __builtin_bit_cast(unsigned, x);
  unsigned r = u + 0x7fffu + ((u >> 16) & 1u);
  return (short)(r >> 16);
}
__device__ __forceinline__ float bf2f(short s) {
  unsigned u = ((unsigned)(unsigned short)s) << 16;
  return __builtin_bit_cast(float, u);
}

// ---- prep: W1/W2 (both layers) -> bf16 fragment-major [kg][col][8] ----
__global__ void prep_weights(const float* __restrict__ W1, const float* __restrict__ W2,
                             short* __restrict__ out) {
  const int t = blockIdx.x * 256 + threadIdx.x;
  const int l = t / WLAYER_SH;
  const int r = t % WLAYER_SH;
  float v;
  if (r < W1T_SH) {
    const int kg = r >> 10, col = (r >> 3) & 127, j = r & 7;
    v = W1[(size_t)l * C1 * DD + (size_t)(kg * 8 + j) * DD + col];
  } else {
    const int r2 = r - W1T_SH;
    const int kg = r2 >> 10, col = (r2 >> 3) & 127, j = r2 & 7;
    v = W2[(size_t)l * 2 * DD * DD + (size_t)(kg * 8 + j) * DD + col];
  }
  out[t] = f2bf(v);
}

// ---- prep: features f32 -> bf16 table ----
__global__ void feat2bf(const float* __restrict__ f, short* __restrict__ o) {
  const size_t i = ((size_t)blockIdx.x * 256 + threadIdx.x) * 4;
  const float4 v = *reinterpret_cast<const float4*>(f + i);
  short4v s; s[0] = f2bf(v.x); s[1] = f2bf(v.y); s[2] = f2bf(v.z); s[3] = f2bf(v.w);
  *reinterpret_cast<short4v*>(o + i) = s;
}

// ---- fused TGN layer: prev is ALWAYS bf16 [N][128]; OUTBF selects tmp(bf16)/out(f32) ----
template<bool OUTBF>
__global__ __launch_bounds__(256, 7) void tgn(
    const short* __restrict__ prevb,  // bf16 gather table == GEMM2-A rows
    const float* __restrict__ edge,   // [N, K, DE]
    const float* __restrict__ timef,  // [N, K, DT]
    const short* __restrict__ wT,     // [W1T | W2T] bf16 fragment-major
    const float* __restrict__ b1g,    // [128]
    const float* __restrict__ b2g,    // [128]
    const int* __restrict__ idxg,     // [N, K]
    void* __restrict__ out_)          // [N, D]
{
  __shared__ short aggb[BN][AB];   // [nbr_sum | e_sum | t_sum], K=192
  __shared__ short hb[BN][HB];     // relu(agg@W1+b1)

  const int t  = threadIdx.x;
  const int n0 = blockIdx.x * BN;   // NN % BN == 0

  // edge/time sums -> aggb[:, 128:192]
  {
    const int c4 = (t & 7) * 4;
    const int nl = t >> 3;  // 0..31
    const float* ep = edge  + (size_t)(n0 + nl) * KK * DEE + c4;
    const float* tp = timef + (size_t)(n0 + nl) * KK * DTT + c4;
    float e0=0,e1=0,e2=0,e3=0, s0=0,s1=0,s2=0,s3=0;
    #pragma unroll
    for (int j = 0; j < KK; ++j) {
      const float4 ev = *reinterpret_cast<const float4*>(ep + j * DEE);
      const float4 tv = *reinterpret_cast<const float4*>(tp + j * DTT);
      e0 += ev.x; e1 += ev.y; e2 += ev.z; e3 += ev.w;
      s0 += tv.x; s1 += tv.y; s2 += tv.z; s3 += tv.w;
    }
    short4v eo; eo[0]=f2bf(e0); eo[1]=f2bf(e1); eo[2]=f2bf(e2); eo[3]=f2bf(e3);
    short4v so; so[0]=f2bf(s0); so[1]=f2bf(s1); so[2]=f2bf(s2); so[3]=f2bf(s3);
    *reinterpret_cast<short4v*>(&aggb[nl][DD + c4])       = eo;
    *reinterpret_cast<short4v*>(&aggb[nl][DD + DEE + c4]) = so;
  }

  // neighbor gather-sum (bf16 rows) -> aggb[:, 0:128]
  {
    const int d4 = (t & 31) * 4;
    for (int nl = t >> 5; nl < BN; nl += 8) {
      const int4* ip = reinterpret_cast<const int4*>(idxg + (size_t)(n0 + nl) * KK);
      const int4 i0 = ip[0], i1 = ip[1], i2 = ip[2], i3 = ip[3];
      const int rows[16] = {i0.x, i0.y, i0.z, i0.w, i1.x, i1.y, i1.z, i1.w,
                            i2.x, i2.y, i2.z, i2.w, i3.x, i3.y, i3.z, i3.w};
      float a0=0, a1=0, a2=0, a3=0;
      #pragma unroll
      for (int j = 0; j < 16; ++j) {
        const short4v v = *reinterpret_cast<const short4v*>(prevb + (size_t)rows[j] * DD + d4);
        a0 += bf2f(v[0]); a1 += bf2f(v[1]); a2 += bf2f(v[2]); a3 += bf2f(v[3]);
      }
      short4v o; o[0]=f2bf(a0); o[1]=f2bf(a1); o[2]=f2bf(a2); o[3]=f2bf(a3);
      *reinterpret_cast<short4v*>(&aggb[nl][d4]) = o;
    }
  }
  __syncthreads();  // aggb ready

  const int lane = t & 63;
  const int wv   = t >> 6;
  const int lr   = lane & 15;
  const int lg   = lane >> 4;
  const int n0w  = wv * 32;

  // ---- GEMM1: h = relu(aggb @ W1 + b1) -> hb ----
  {
    f32x4 acc[2][2];
    #pragma unroll
    for (int nt = 0; nt < 2; ++nt) {
      const float bv = b1g[n0w + nt * 16 + lr];
      acc[0][nt] = (f32x4){bv, bv, bv, bv};
      acc[1][nt] = (f32x4){bv, bv, bv, bv};
    }
    #pragma unroll
    for (int ks = 0; ks < 6; ++ks) {
      const bfrag a0 = *reinterpret_cast<const bfrag*>(&aggb[lr][ks * 32 + lg * 8]);
      const bfrag a1 = *reinterpret_cast<const bfrag*>(&aggb[16 + lr][ks * 32 + lg * 8]);
      const short* wp = wT + ((size_t)((ks * 4 + lg) * 128) + n0w + lr) * 8;
      const bfrag bb0 = *reinterpret_cast<const bfrag*>(wp);
      const bfrag bb1 = *reinterpret_cast<const bfrag*>(wp + 16 * 8);
      acc[0][0] = __builtin_amdgcn_mfma_f32_16x16x32_bf16(a0, bb0, acc[0][0], 0, 0, 0);
      acc[1][0] = __builtin_amdgcn_mfma_f32_16x16x32_bf16(a1, bb0, acc[1][0], 0, 0, 0);
      acc[0][1] = __builtin_amdgcn_mfma_f32_16x16x32_bf16(a0, bb1, acc[0][1], 0, 0, 0);
      acc[1][1] = __builtin_amdgcn_mfma_f32_16x16x32_bf16(a1, bb1, acc[1][1], 0, 0, 0);
    }
    #pragma unroll
    for (int mt = 0; mt < 2; ++mt)
      #pragma unroll
      for (int nt = 0; nt < 2; ++nt)
        #pragma unroll
        for (int r = 0; r < 4; ++r)
          hb[mt * 16 + lg * 4 + r][n0w + nt * 16 + lr] = f2bf(fmaxf(acc[mt][nt][r], 0.f));
  }
  __syncthreads();  // hb ready

  // ---- GEMM2: out = [prev | h] @ W2 + b2 ; prev A-frags direct from global ----
  {
    const short* w2T = wT + W1T_SH;
    f32x4 acc[2][2];
    #pragma unroll
    for (int nt = 0; nt < 2; ++nt) {
      const float bv = b2g[n0w + nt * 16 + lr];
      acc[0][nt] = (f32x4){bv, bv, bv, bv};
      acc[1][nt] = (f32x4){bv, bv, bv, bv};
    }
    #pragma unroll
    for (int ks = 0; ks < 8; ++ks) {
      bfrag a0, a1;
      if (ks < 4) {  // prev rows: block-local, L1-resident after first wave
        a0 = *reinterpret_cast<const bfrag*>(prevb + (size_t)(n0 + lr) * DD + ks * 32 + lg * 8);
        a1 = *reinterpret_cast<const bfrag*>(prevb + (size_t)(n0 + 16 + lr) * DD + ks * 32 + lg * 8);
      } else {       // h from LDS
        a0 = *reinterpret_cast<const bfrag*>(&hb[lr][(ks - 4) * 32 + lg * 8]);
        a1 = *reinterpret_cast<const bfrag*>(&hb[16 + lr][(ks - 4) * 32 + lg * 8]);
      }
      const short* wp = w2T + ((size_t)((ks * 4 + lg) * 128) + n0w + lr) * 8;
      const bfrag bb0 = *reinterpret_cast<const bfrag*>(wp);
      const bfrag bb1 = *reinterpret_cast<const bfrag*>(wp + 16 * 8);
      acc[0][0] = __builtin_amdgcn_mfma_f32_16x16x32_bf16(a0, bb0, acc[0][0], 0, 0, 0);
      acc[1][0] = __builtin_amdgcn_mfma_f32_16x16x32_bf16(a1, bb0, acc[1][0], 0, 0, 0);
      acc[0][1] = __builtin_amdgcn_mfma_f32_16x16x32_bf16(a0, bb1, acc[0][1], 0, 0, 0);
      acc[1][1] = __builtin_amdgcn_mfma_f32_16x16x32_bf16(a1, bb1, acc[1][1], 0, 0, 0);
    }
    #pragma unroll
    for (int mt = 0; mt < 2; ++mt)
      #pragma unroll
      for (int nt = 0; nt < 2; ++nt)
        #pragma unroll
        for (int r = 0; r < 4; ++r) {
          const float v = acc[mt][nt][r];
          const size_t grow = (size_t)(n0 + mt * 16 + lg * 4 + r);
          const int    gcol = n0w + nt * 16 + lr;
          if constexpr (OUTBF) ((short*)out_)[grow * DD + gcol] = f2bf(v);
          else                 ((float*)out_)[grow * DD + gcol] = v;
        }
  }
}

extern "C" void kernel_launch(void* const* d_in, const int* in_sizes, int n_in,
                              void* d_out, int out_size, void* d_ws, size_t ws_size,
                              hipStream_t stream) {
  const float* features = (const float*)d_in[0];
  const float* edge     = (const float*)d_in[1];
  const float* timef    = (const float*)d_in[2];
  const float* W1       = (const float*)d_in[3];
  const float* b1       = (const float*)d_in[4];
  const float* W2       = (const float*)d_in[5];
  const float* b2       = (const float*)d_in[6];
  const int*   idx      = (const int*)d_in[7];
  float* outp = (float*)d_out;

  short* wT     = (short*)d_ws;
  short* tmp    = (short*)((char*)d_ws + TMP_OFF_B);
  short* featbf = (short*)((char*)d_ws + FBF_OFF_B);

  dim3 block(256);

  prep_weights<<<dim3(WTOT_SH / 256), block, 0, stream>>>(W1, W2, wT);
  feat2bf<<<dim3(NN * DD / 4 / 256), block, 0, stream>>>(features, featbf);

  // layer 0: featbf -> tmp (bf16)
  tgn<true><<<dim3(GRID), block, 0, stream>>>(
      featbf, edge, timef, wT, b1, b2, idx, tmp);

  // layer 1: tmp -> out (f32)
  tgn<false><<<dim3(GRID), block, 0, stream>>>(
      tmp,
      edge  + (size_t)NN * KK * DEE,
      timef + (size_t)NN * KK * DTT,
      wT + WLAYER_SH,
      b1 + DD,
      b2 + DD,
      idx + (size_t)NN * KK,
      outp);
}